// Round 14
// baseline (136.156 us; speedup 1.0000x reference)
//
#include <hip/hip_runtime.h>
#include <math.h>

#define BTOT   32768
#define LAT    128
#define H      17
#define G4     68      // 4*H
#define TSTEPS 50
#define NPR    102     // projection rows: 68 (W_ih) + 17 (W_h0) + 17 (W_c0)
#define WPAD   40      // Wbuf row stride (k-quarter staging)
#define XPAD   132

#define NW     4              // waves per block
#define SETS   4              // row-sets per wave (pipeline depth 4)
#define RPW    12             // rows per wave = SETS*3
#define RPB    48             // rows per block
#define TPB    256

#define LOG2E 1.4426950408889634f

// x_tile stride 132 (528B ≡ +4 banks/row): rows r,r+8 alias -> key (r>>3)&3.
#define XSWZ(r, c4)   ((c4) ^ ((((r) >> 3) & 3) << 2))
// Wbuf stride 40 (160B ≡ +8 banks/row): rows r,r+4 alias -> key (row>>2)&3.
#define WSWZ(row, c4) ((c4) ^ ((((row) >> 2) & 3) << 2))

// v_exp_f32 IS exp2 -- gates are pre-scaled by -log2e / +2log2e so no per-step mul.
__device__ __forceinline__ float exp2g(float x) {
    float r; asm("v_exp_f32 %0, %1" : "=v"(r) : "v"(x)); return r;
}
#define FMAC(acc, w, h) asm("v_fmac_f32 %0, %1, %2" : "+v"(acc) : "v"(w), "v"(h))

#define FQ(Q, HV) \
    FMAC(ai,Wi[4*Q+0],HV.x); FMAC(af,Wf[4*Q+0],HV.x); FMAC(ag,Wg[4*Q+0],HV.x); FMAC(ao,Wo[4*Q+0],HV.x); \
    FMAC(ai,Wi[4*Q+1],HV.y); FMAC(af,Wf[4*Q+1],HV.y); FMAC(ag,Wg[4*Q+1],HV.y); FMAC(ao,Wo[4*Q+1],HV.y); \
    FMAC(ai,Wi[4*Q+2],HV.z); FMAC(af,Wf[4*Q+2],HV.z); FMAC(ag,Wg[4*Q+2],HV.z); FMAC(ao,Wo[4*Q+2],HV.z); \
    FMAC(ai,Wi[4*Q+3],HV.w); FMAC(af,Wf[4*Q+3],HV.w); FMAC(ag,Wg[4*Q+3],HV.w); FMAC(ao,Wo[4*Q+3],HV.w);

// read one h-row (17 floats) from wave-private LDS into a frag
#define XR(hb, F0, F1, F2, F3, F4) do { \
    F0 = *(const float4*)&(hb)[0];  F1 = *(const float4*)&(hb)[4]; \
    F2 = *(const float4*)&(hb)[8];  F3 = *(const float4*)&(hb)[12]; \
    F4 = (hb)[16]; } while (0)

// full gate step for set S consuming frag F*; updates hS[S], cS[S]
#define CSTEP(S, F0, F1, F2, F3, F4) do { \
    float ai = xgi[S], af = xgf[S], ag = xgg[S], ao = xgo[S]; \
    FQ(0, F0) FQ(1, F1) FQ(2, F2) FQ(3, F3) \
    FMAC(ai,Wi[16],F4); FMAC(af,Wf[16],F4); FMAC(ag,Wg[16],F4); FMAC(ao,Wo[16],F4); \
    const float ig = __builtin_amdgcn_rcpf(1.0f + exp2g(ai)); \
    const float fg = __builtin_amdgcn_rcpf(1.0f + exp2g(af)); \
    const float og = __builtin_amdgcn_rcpf(1.0f + exp2g(ao)); \
    const float tg = __builtin_amdgcn_rcpf(exp2g(ag) + 1.0f); \
    const float gv = fmaf(-2.0f, tg, 1.0f); \
    cS[S] = fmaf(fg, cS[S], ig * gv); \
    const float tc = __builtin_amdgcn_rcpf(exp2g(cS[S] * (2.0f * LOG2E)) + 1.0f); \
    hS[S] = og * fmaf(-2.0f, tc, 1.0f); } while (0)

// (256,2): reg cap 256 -> structurally no spill (R11/R12 lesson).
__global__ __launch_bounds__(TPB, 2)
void lstm_fused(const float* __restrict__ x,
                const float* __restrict__ W_h0, const float* __restrict__ b_h0,
                const float* __restrict__ W_c0, const float* __restrict__ b_c0,
                const float* __restrict__ W_ih, const float* __restrict__ W_hh,
                const float* __restrict__ b_ih, const float* __restrict__ b_hh,
                float* __restrict__ out)
{
    __shared__ __align__(16) float x_tile[RPB][XPAD];   // 25.3 KB
    __shared__ __align__(16) float Wbuf[NPR][WPAD];     // 16.3 KB (one k-quarter)
    __shared__ __align__(16) float Wl[G4 * H];          //  4.6 KB
    __shared__ __align__(16) float hbuf[NW][RPW][20];   //  3.8 KB
    // total 50.1 KB -> 3 blocks/CU; grid 683 <= 768 slots -> fully co-resident

    const int t    = threadIdx.x;
    const int w    = t >> 6;
    const int lane = t & 63;
    const bool active = lane < 3 * H;         // 51
    const int rl = active ? (lane / H) : 0;   // 0..2
    const int j  = active ? (lane % H) : 0;   // 0..16
    const int r0 = w * RPW + rl;              // set-A local row
    const int grow0 = blockIdx.x * RPB;

    int grows[SETS]; bool vS[SETS];
#pragma unroll
    for (int s = 0; s < SETS; ++s) {
        int g = grow0 + r0 + 3 * s;
        vS[s] = active && (g < BTOT);
        grows[s] = (g < BTOT) ? g : (BTOT - 1);
    }

    // ---- stage x tile + W_hh ----
    for (int i = t; i < RPB * 32; i += TPB) {
        int rr = i >> 5, c4 = (i & 31) * 4;
        int gr = grow0 + rr; if (gr >= BTOT) gr = BTOT - 1;
        *(float4*)&x_tile[rr][XSWZ(rr, c4)] = *(const float4*)(x + (size_t)gr * LAT + c4);
    }
    for (int i = t; i < G4 * H; i += TPB) Wl[i] = W_hh[i];

    // ---- phase 1: projections for 4 sets, four k-quarters of 32 ----
    float acc[24];
#pragma unroll
    for (int s = 0; s < 24; ++s) acc[s] = 0.0f;
    const int rows6[6] = { j, 17 + j, 34 + j, 51 + j, 68 + j, 85 + j };
    for (int qh = 0; qh < 4; ++qh) {
        __syncthreads();  // qh=0: x_tile/Wl ready; else WAR on Wbuf
        for (int i = t; i < NPR * 8; i += TPB) {
            int row = i >> 3, c4 = (i & 7) * 4;
            const float* src = (row < G4) ? (W_ih + row * LAT)
                             : (row < 85) ? (W_h0 + (row - G4) * LAT)
                                          : (W_c0 + (row - 85) * LAT);
            *(float4*)&Wbuf[row][WSWZ(row, c4)] = *(const float4*)(src + qh * 32 + c4);
        }
        __syncthreads();
        for (int kb = 0; kb < 8; ++kb) {
            const int xc = qh * 32 + kb * 4;
            float4 xv[SETS];
#pragma unroll
            for (int s = 0; s < SETS; ++s) {
                const int rr = r0 + 3 * s;
                xv[s] = *(const float4*)&x_tile[rr][XSWZ(rr, xc)];
            }
#pragma unroll
            for (int p = 0; p < 6; ++p) {
                const int row = rows6[p];
                float4 wv = *(const float4*)&Wbuf[row][WSWZ(row, kb * 4)];
#pragma unroll
                for (int s = 0; s < SETS; ++s) {
                    acc[s*6+p] = fmaf(xv[s].x, wv.x, acc[s*6+p]);
                    acc[s*6+p] = fmaf(xv[s].y, wv.y, acc[s*6+p]);
                    acc[s*6+p] = fmaf(xv[s].z, wv.z, acc[s*6+p]);
                    acc[s*6+p] = fmaf(xv[s].w, wv.w, acc[s*6+p]);
                }
            }
        }
    }

    // ---- biases + exp2 pre-scaling (i,f,o: -log2e; g: +2log2e) ----
    const float bi0 = b_ih[j]      + b_hh[j];
    const float bi1 = b_ih[17 + j] + b_hh[17 + j];
    const float bi2 = b_ih[34 + j] + b_hh[34 + j];
    const float bi3 = b_ih[51 + j] + b_hh[51 + j];
    float xgi[SETS], xgf[SETS], xgg[SETS], xgo[SETS], hS[SETS], cS[SETS];
#pragma unroll
    for (int s = 0; s < SETS; ++s) {
        xgi[s] = (acc[s*6+0] + bi0) * (-LOG2E);
        xgf[s] = (acc[s*6+1] + bi1) * (-LOG2E);
        xgg[s] = (acc[s*6+2] + bi2) * (2.0f * LOG2E);
        xgo[s] = (acc[s*6+3] + bi3) * (-LOG2E);
        hS[s]  =  acc[s*6+4] + b_h0[j];
        cS[s]  =  acc[s*6+5] + b_c0[j];
    }

    // ---- W_hh rows -> registers, pre-scaled per gate ----
    float Wi[H], Wf[H], Wg[H], Wo[H];
#pragma unroll
    for (int k = 0; k < H; ++k) {
        Wi[k] = Wl[(0 * H + j) * H + k] * (-LOG2E);
        Wf[k] = Wl[(1 * H + j) * H + k] * (-LOG2E);
        Wg[k] = Wl[(2 * H + j) * H + k] * (2.0f * LOG2E);
        Wo[k] = Wl[(3 * H + j) * H + k] * (-LOG2E);
        asm volatile("" : "+v"(Wi[k]), "+v"(Wf[k]), "+v"(Wg[k]), "+v"(Wo[k]));
    }

    // ---- phase 2: depth-4 pipeline, zero barriers ----
    const float* hb0 = &hbuf[w][0 + rl][0];
    const float* hb1 = &hbuf[w][3 + rl][0];
    const float* hb2 = &hbuf[w][6 + rl][0];
    const float* hb3 = &hbuf[w][9 + rl][0];
    float* orow0 = out + (size_t)grows[0] * (TSTEPS * H) + j;
    float* orow1 = out + (size_t)grows[1] * (TSTEPS * H) + j;
    float* orow2 = out + (size_t)grows[2] * (TSTEPS * H) + j;
    float* orow3 = out + (size_t)grows[3] * (TSTEPS * H) + j;

    float4 f0a, f1a, f2a, f3a; float f4a;   // frag buffer 0
    float4 f0b, f1b, f2b, f3b; float f4b;   // frag buffer 1

    // prologue: write all initial h, then prefetch A into buf0
    if (active) {
        hbuf[w][0 + rl][j] = hS[0];
        hbuf[w][3 + rl][j] = hS[1];
        hbuf[w][6 + rl][j] = hS[2];
        hbuf[w][9 + rl][j] = hS[3];
    }
    XR(hb0, f0a, f1a, f2a, f3a, f4a);

    for (int tt = 0; tt < TSTEPS; ++tt) {
        XR(hb1, f0b, f1b, f2b, f3b, f4b);            // B for this step
        CSTEP(0, f0a, f1a, f2a, f3a, f4a);           // A (frag loaded last iter)
        if (active) hbuf[w][0 + rl][j] = hS[0];
        if (vS[0]) orow0[0] = hS[0];
        orow0 += H;

        XR(hb2, f0a, f1a, f2a, f3a, f4a);            // C for this step
        CSTEP(1, f0b, f1b, f2b, f3b, f4b);           // B
        if (active) hbuf[w][3 + rl][j] = hS[1];
        if (vS[1]) orow1[0] = hS[1];
        orow1 += H;

        XR(hb3, f0b, f1b, f2b, f3b, f4b);            // D for this step
        CSTEP(2, f0a, f1a, f2a, f3a, f4a);           // C
        if (active) hbuf[w][6 + rl][j] = hS[2];
        if (vS[2]) orow2[0] = hS[2];
        orow2 += H;

        XR(hb0, f0a, f1a, f2a, f3a, f4a);            // A for NEXT step
        CSTEP(3, f0b, f1b, f2b, f3b, f4b);           // D
        if (active) hbuf[w][9 + rl][j] = hS[3];
        if (vS[3]) orow3[0] = hS[3];
        orow3 += H;
    }
}

extern "C" void kernel_launch(void* const* d_in, const int* in_sizes, int n_in,
                              void* d_out, int out_size, void* d_ws, size_t ws_size,
                              hipStream_t stream)
{
    const float* x    = (const float*)d_in[0];
    const float* W_h0 = (const float*)d_in[1];
    const float* b_h0 = (const float*)d_in[2];
    const float* W_c0 = (const float*)d_in[3];
    const float* b_c0 = (const float*)d_in[4];
    const float* W_ih = (const float*)d_in[5];
    const float* W_hh = (const float*)d_in[6];
    const float* b_ih = (const float*)d_in[7];
    const float* b_hh = (const float*)d_in[8];
    float* out = (float*)d_out;

    (void)d_ws; (void)ws_size;  // no workspace used

    const int nblk = (BTOT + RPB - 1) / RPB;   // 683
    hipLaunchKernelGGL(lstm_fused, dim3(nblk), dim3(TPB), 0, stream,
                       x, W_h0, b_h0, W_c0, b_c0, W_ih, W_hh, b_ih, b_hh, out);
}